// Round 6
// baseline (356.367 us; speedup 1.0000x reference)
//
#include <hip/hip_runtime.h>
#include <hip/hip_bf16.h>
#include <stdint.h>

// AFT-full, MI355X. Shapes: x[64,1024,512], W*[512,512], pos_bias[1024,1024].
//   q,k,v = x W^T + b ; out = sigmoid(q) * (eb@(e^k*v)) / (eb@e^k), eb=exp(pos_bias)
// Pipeline:
//   K0: eb = bf16(exp(pos_bias));  K1: xb = bf16(x), Wb = [Wq; Wk/Wv interleaved]
//   P1: fused QKV GEMM -> s (sigmoid(q), natural), Z (ekv/ek K-major interleaved)
//   P2: merged GEMM C[i,n] = eb @ Z^T, register-local num/den division epilogue.
// Both GEMMs: 256x256x64 tile, 8 waves, 128 KiB LDS, **8-phase counted-vmcnt
// schedule** (T3+T4+T5): per 2 K-tiles, 8 phases of {ds_read subtile | stage 1
// half-tile | barrier | setprio + 16 MFMA | barrier}; vmcnt(6) on even phases
// only (3 half-tiles in flight across barriers, never drained in-loop).
// LDS halves are K-split [256 rows][32 cols]; frag reads are bank-uniform.
// Workspace: eb 2MiB@0, Wb 1.5MiB@2MiB, xb 64MiB@4MiB, s 64MiB@68MiB, Z 128MiB@132MiB.

#define NSEQ 1024
#define DM   512

typedef __attribute__((ext_vector_type(8))) short bf16x8;
typedef __attribute__((ext_vector_type(4))) float f32x4;

static __device__ __forceinline__ float b2f(unsigned short u) {
    union { uint32_t i; float f; } c; c.i = ((uint32_t)u) << 16; return c.f;
}
static __device__ __forceinline__ unsigned short f2b(float f) {
    union { float f; uint32_t i; } c; c.f = f;
    uint32_t r = c.i + 0x7FFFu + ((c.i >> 16) & 1u);
    return (unsigned short)(r >> 16);
}
static __device__ __forceinline__ void gl_lds16(const unsigned short* g, unsigned short* l) {
    __builtin_amdgcn_global_load_lds(
        (const __attribute__((address_space(1))) unsigned int*)(g),
        (__attribute__((address_space(3))) unsigned int*)(l), 16, 0, 0);
}

__global__ void k_eb(const float* __restrict__ pb, unsigned short* __restrict__ eb) {
    int i = blockIdx.x * 256 + threadIdx.x;
    float4 v = reinterpret_cast<const float4*>(pb)[i];
    union { unsigned short u[4]; uint2 p; } o;
    o.u[0] = f2b(__expf(v.x)); o.u[1] = f2b(__expf(v.y));
    o.u[2] = f2b(__expf(v.z)); o.u[3] = f2b(__expf(v.w));
    reinterpret_cast<uint2*>(eb)[i] = o.p;
}

__global__ void k_cvt(const float* __restrict__ src, unsigned short* __restrict__ dst) {
    int i = blockIdx.x * 256 + threadIdx.x;
    const float4* p = reinterpret_cast<const float4*>(src) + (size_t)i * 2;
    float4 f0 = p[0], f1 = p[1];
    union { unsigned short u[8]; int4 v; } o;
    o.u[0]=f2b(f0.x); o.u[1]=f2b(f0.y); o.u[2]=f2b(f0.z); o.u[3]=f2b(f0.w);
    o.u[4]=f2b(f1.x); o.u[5]=f2b(f1.y); o.u[6]=f2b(f1.z); o.u[7]=f2b(f1.w);
    reinterpret_cast<int4*>(dst)[i] = o.v;
}

__global__ void k_cvt_kv(const float* __restrict__ src, unsigned short* __restrict__ Wb,
                         int toff) {
    int i = blockIdx.x * 256 + threadIdx.x;
    int r = i >> 6, c8 = i & 63;
    const float4* p = reinterpret_cast<const float4*>(src + (size_t)r * DM + c8 * 8);
    float4 f0 = p[0], f1 = p[1];
    union { unsigned short u[8]; int4 v; } o;
    o.u[0]=f2b(f0.x); o.u[1]=f2b(f0.y); o.u[2]=f2b(f0.z); o.u[3]=f2b(f0.w);
    o.u[4]=f2b(f1.x); o.u[5]=f2b(f1.y); o.u[6]=f2b(f1.z); o.u[7]=f2b(f1.w);
    int r2 = 512 + ((r >> 6) << 7) + toff + (r & 63);
    *reinterpret_cast<int4*>(&Wb[(size_t)r2 * DM + c8 * 8]) = o.v;
}

// ---------------- shared 8-phase K-loop ----------------
// LDS (shorts): A(s,k) = smem + s*16384 + k*8192 ; B(s,k) = +32768 same.
// Each half = [256 rows][32 cols] linear; staged by 16 chunks of 16 rows.
// Ledger (waits vmcnt(6) at even phases force all but 3 newest halves):
//   tile T=2i (slot0) k0 staged prev ph3/4, k1 prev ph5/6; U=2i+1 (slot1)
//   k0 staged prev ph7/8, k1 cur ph1/2. Reads: ph1-2 slot0-k0, ph3-4 slot0-k1,
//   ph5-6 slot1-k0, ph7-8 slot1-k1. All guards verified; WAR separated by >=1
//   barrier. Tail stages garbage from column (t & (NT-1))*64 — in-bounds,
//   never consumed, keeps every iteration identical.
template<int NT>
static __device__ __forceinline__ void gemm_8ph(
    const unsigned short* __restrict__ Abase,   // A + row0*lda
    const unsigned short* __restrict__ Bbase,   // B + row0*ldb
    int lda, int ldb, unsigned short* smem, f32x4 (&acc)[8][4],
    int wave, int lane)
{
    const int wr = wave >> 2, wq = wave & 3;
    const int lrow = lane & 15, lkg = lane >> 4;
    const int c0 = wave * 2;                    // this wave's 2 chunks per half
    const int srow = lane >> 2;                 // row within 16-row chunk
    const int sslot = lane & 3;                 // 8-short slot within 32-col row

    auto stageA = [&](int s, int k, int t) {
        int kcol = ((t & (NT - 1)) << 6) + (k << 5) + sslot * 8;
        unsigned short* d = smem + s * 16384 + k * 8192;
        #pragma unroll
        for (int q = 0; q < 2; ++q) {
            int c = c0 + q;
            gl_lds16(Abase + (size_t)(c * 16 + srow) * lda + kcol, d + c * 512);
        }
    };
    auto stageB = [&](int s, int k, int t) {
        int kcol = ((t & (NT - 1)) << 6) + (k << 5) + sslot * 8;
        unsigned short* d = smem + 32768 + s * 16384 + k * 8192;
        #pragma unroll
        for (int q = 0; q < 2; ++q) {
            int c = c0 + q;
            gl_lds16(Bbase + (size_t)(c * 16 + srow) * ldb + kcol, d + c * 512);
        }
    };
    auto loadA = [&](int s, int kk, int h, bf16x8* af) {
        const unsigned short* base = smem + s * 16384 + kk * 8192;
        #pragma unroll
        for (int mi = 0; mi < 4; ++mi) {
            int row = wr * 128 + h * 64 + mi * 16 + lrow;
            af[mi] = *reinterpret_cast<const bf16x8*>(base + row * 32 + lkg * 8);
        }
    };
    auto loadB = [&](int s, int kk, bf16x8* bf) {
        const unsigned short* base = smem + 32768 + s * 16384 + kk * 8192;
        #pragma unroll
        for (int ni = 0; ni < 4; ++ni) {
            int row = wq * 64 + ni * 16 + lrow;
            bf[ni] = *reinterpret_cast<const bf16x8*>(base + row * 32 + lkg * 8);
        }
    };
    auto mfma16 = [&](int h, bf16x8* af, bf16x8* bf) {
        __builtin_amdgcn_s_setprio(1);
        #pragma unroll
        for (int mi = 0; mi < 4; ++mi)
            #pragma unroll
            for (int ni = 0; ni < 4; ++ni)
                acc[h * 4 + mi][ni] = __builtin_amdgcn_mfma_f32_16x16x32_bf16(
                    af[mi], bf[ni], acc[h * 4 + mi][ni], 0, 0, 0);
        __builtin_amdgcn_s_setprio(0);
    };

    // prologue: tile0 all 4 halves + tile1 k0 halves (12 loads/thread)
    stageA(0, 0, 0); stageB(0, 0, 0); stageA(0, 1, 0); stageB(0, 1, 0);
    stageA(1, 0, 1); stageB(1, 0, 1);
    asm volatile("s_waitcnt vmcnt(8)" ::: "memory");   // forces tile0-k0 A,B
    __builtin_amdgcn_s_barrier();

    #pragma unroll 1
    for (int i = 0; i < NT / 2; ++i) {
        const int U = 2 * i + 1, T2 = 2 * i + 2, U2 = 2 * i + 3;
        bf16x8 af[4], bfr[4];
        // ph1: slot0 k0 h0 | stage slot1-A-k1 (tile U)
        loadA(0, 0, 0, af); loadB(0, 0, bfr); stageA(1, 1, U);
        __builtin_amdgcn_s_barrier(); mfma16(0, af, bfr); __builtin_amdgcn_s_barrier();
        // ph2: slot0 k0 h1 | stage slot1-B-k1
        loadA(0, 0, 1, af); stageB(1, 1, U);
        asm volatile("s_waitcnt vmcnt(6)" ::: "memory");
        __builtin_amdgcn_s_barrier(); mfma16(1, af, bfr); __builtin_amdgcn_s_barrier();
        // ph3: slot0 k1 h0 | stage slot0-A-k0 (tile T2)
        loadA(0, 1, 0, af); loadB(0, 1, bfr); stageA(0, 0, T2);
        __builtin_amdgcn_s_barrier(); mfma16(0, af, bfr); __builtin_amdgcn_s_barrier();
        // ph4: slot0 k1 h1 | stage slot0-B-k0
        loadA(0, 1, 1, af); stageB(0, 0, T2);
        asm volatile("s_waitcnt vmcnt(6)" ::: "memory");
        __builtin_amdgcn_s_barrier(); mfma16(1, af, bfr); __builtin_amdgcn_s_barrier();
        // ph5: slot1 k0 h0 | stage slot0-A-k1
        loadA(1, 0, 0, af); loadB(1, 0, bfr); stageA(0, 1, T2);
        __builtin_amdgcn_s_barrier(); mfma16(0, af, bfr); __builtin_amdgcn_s_barrier();
        // ph6: slot1 k0 h1 | stage slot0-B-k1
        loadA(1, 0, 1, af); stageB(0, 1, T2);
        asm volatile("s_waitcnt vmcnt(6)" ::: "memory");
        __builtin_amdgcn_s_barrier(); mfma16(1, af, bfr); __builtin_amdgcn_s_barrier();
        // ph7: slot1 k1 h0 | stage slot1-A-k0 (tile U2)
        loadA(1, 1, 0, af); loadB(1, 1, bfr); stageA(1, 0, U2);
        __builtin_amdgcn_s_barrier(); mfma16(0, af, bfr); __builtin_amdgcn_s_barrier();
        // ph8: slot1 k1 h1 | stage slot1-B-k0
        loadA(1, 1, 1, af); stageB(1, 0, U2);
        asm volatile("s_waitcnt vmcnt(6)" ::: "memory");
        __builtin_amdgcn_s_barrier(); mfma16(1, af, bfr); __builtin_amdgcn_s_barrier();
    }
    // drain lingering (garbage-tail) gl_lds before anyone reuses LDS
    asm volatile("s_waitcnt vmcnt(0)" ::: "memory");
    __builtin_amdgcn_s_barrier();
}

// ---------------- P1: fused QKV projection ----------------
// 1536 blocks = 256 mtiles x 6 etiles; XCD-chunked, etile fastest.
__launch_bounds__(512)
__global__ void k_qkv(const unsigned short* __restrict__ xb,
                      const unsigned short* __restrict__ Wb,
                      const float* __restrict__ bq, const float* __restrict__ bk,
                      const float* __restrict__ bv,
                      unsigned short* __restrict__ s_out,
                      unsigned short* __restrict__ Z)
{
    extern __shared__ unsigned short smem[];          // 128 KiB
    const int bid = blockIdx.x;
    const int logical = (bid & 7) * 192 + (bid >> 3);
    const int mtile = logical / 6, etile = logical % 6;
    const int brow = mtile * 256;
    const int erow = etile * 256;
    const bool isq = (etile < 2);

    const int tid = threadIdx.x;
    const int lane = tid & 63, wave = tid >> 6;
    const int wr = wave >> 2, wq = wave & 3;
    const int lrow = lane & 15, lkg = lane >> 4;

    f32x4 acc[8][4];
    const f32x4 z4 = {0.f, 0.f, 0.f, 0.f};
    #pragma unroll
    for (int a = 0; a < 8; ++a)
        #pragma unroll
        for (int c = 0; c < 4; ++c) acc[a][c] = z4;

    gemm_8ph<8>(xb + (size_t)brow * DM, Wb + (size_t)erow * DM, DM, DM,
                smem, acc, wave, lane);

    unsigned short* T = smem;                          // [*][136] overlay
    if (isq) {
        const int ecol = etile * 256;
        #pragma unroll
        for (int pp = 0; pp < 2; ++pp) {
            __syncthreads();
            if ((wq >> 1) == pp) {
                #pragma unroll
                for (int mi = 0; mi < 8; ++mi) {
                    int m0 = wr*128 + mi*16 + lkg*4;
                    #pragma unroll
                    for (int ni = 0; ni < 4; ++ni) {
                        int nl = (wq & 1) * 64 + ni*16 + lrow;
                        float bia = bq[ecol + pp*128 + nl];
                        #pragma unroll
                        for (int r = 0; r < 4; ++r) {
                            float tq = acc[mi][ni][r] + bia;
                            float sg = __builtin_amdgcn_rcpf(1.f + __expf(-tq));
                            T[(m0 + r) * 136 + nl] = f2b(sg);
                        }
                    }
                }
            }
            __syncthreads();
            #pragma unroll
            for (int it = 0; it < 8; ++it) {
                int idx = it * 512 + tid;
                int m = idx >> 4, ng = idx & 15;
                int4 vv = *reinterpret_cast<const int4*>(&T[m * 136 + ng * 8]);
                *reinterpret_cast<int4*>(
                    &s_out[(size_t)(brow + m) * DM + ecol + pp*128 + ng * 8]) = vv;
            }
        }
    } else {
        const int gbase = (etile - 2) * 2;
        const int b = brow >> 10;
        #pragma unroll
        for (int pp = 0; pp < 2; ++pp) {              // m-half
            __syncthreads();
            if (wr == pp) {
                #pragma unroll
                for (int mi = 0; mi < 8; ++mi) {
                    int m0 = mi*16 + lkg*4;
                    #pragma unroll
                    for (int ni = 0; ni < 4; ++ni) {
                        int n = wq*64 + ni*16 + lrow;
                        int sub = (n >> 6) & 1, dr = n & 63;
                        int d = (gbase + (n >> 7)) * 64 + dr;
                        float bia = (sub == 0) ? bk[d] : bv[d];
                        union { unsigned short u[4]; uint2 p; } o;
                        #pragma unroll
                        for (int r = 0; r < 4; ++r) {
                            float tv = acc[mi][ni][r] + bia;
                            o.u[r] = f2b((sub == 0) ? __expf(tv) : tv);
                        }
                        *reinterpret_cast<uint2*>(&T[n * 136 + m0]) = o.p;
                    }
                }
            }
            __syncthreads();
            const int j0 = (brow & (NSEQ - 1)) + pp * 128;
            #pragma unroll
            for (int it = 0; it < 8; ++it) {
                int idx = it * 512 + tid;
                int zr = idx >> 4, jg = idx & 15;
                int gg = zr >> 7, sub2 = (zr >> 6) & 1, dr = zr & 63;
                int d = (gbase + gg) * 64 + dr;
                union { unsigned short u[8]; int4 v; } o;
                if (sub2 == 0) {
                    union { unsigned short u[8]; int4 v; } pe, pv;
                    pe.v = *reinterpret_cast<const int4*>(&T[(gg*128 + dr) * 136 + jg*8]);
                    pv.v = *reinterpret_cast<const int4*>(&T[(gg*128 + 64 + dr) * 136 + jg*8]);
                    #pragma unroll
                    for (int j = 0; j < 8; ++j) o.u[j] = f2b(b2f(pe.u[j]) * b2f(pv.u[j]));
                } else {
                    o.v = *reinterpret_cast<const int4*>(&T[(gg*128 + dr) * 136 + jg*8]);
                }
                int nn = ((d >> 4) << 5) + sub2 * 16 + (d & 15);
                size_t off = ((size_t)(b * NSEQ + nn)) * NSEQ + j0 + jg * 8;
                *reinterpret_cast<int4*>(&Z[off]) = o.v;
            }
        }
    }
}

// ---------------- P2: merged mixing GEMM ----------------
// 1024 blocks = 4 itiles x 256 ntiles, XCD-chunked, itile fastest.
__launch_bounds__(512)
__global__ void k_aft(const unsigned short* __restrict__ eb,
                      const unsigned short* __restrict__ Z,
                      const unsigned short* __restrict__ s_in,
                      float* __restrict__ out)
{
    extern __shared__ unsigned short smem[];          // 128 KiB
    const int bid = blockIdx.x;
    const int logical = (bid & 7) * 128 + (bid >> 3);
    const int itile = logical & 3, ntile = logical >> 2;
    const int i0 = itile * 256;
    const int n0 = ntile * 256;

    const int tid = threadIdx.x;
    const int lane = tid & 63, wave = tid >> 6;
    const int wr = wave >> 2, wq = wave & 3;
    const int lrow = lane & 15, lkg = lane >> 4;

    f32x4 acc[8][4];
    const f32x4 z4 = {0.f, 0.f, 0.f, 0.f};
    #pragma unroll
    for (int a = 0; a < 8; ++a)
        #pragma unroll
        for (int c = 0; c < 4; ++c) acc[a][c] = z4;

    gemm_8ph<16>(eb + (size_t)i0 * NSEQ, Z + (size_t)n0 * NSEQ, NSEQ, NSEQ,
                 smem, acc, wave, lane);

    // epilogue: ni pairs (0,1),(2,3) are (num,den) for the same d
    #pragma unroll
    for (int mi = 0; mi < 8; ++mi) {
        int i = i0 + wr*128 + mi*16 + lkg*4;
        #pragma unroll
        for (int pi = 0; pi < 2; ++pi) {
            int nA = n0 + wq*64 + pi*32 + lrow;
            int b  = nA >> 10, nn = nA & (NSEQ - 1);
            int d  = ((nn >> 5) << 4) + (nn & 15);
            #pragma unroll
            for (int r = 0; r < 4; ++r) {
                size_t o = ((size_t)(b * NSEQ + i + r)) * DM + d;
                float num = acc[mi][pi*2][r];
                float den = acc[mi][pi*2 + 1][r];
                out[o] = b2f(s_in[o]) * num / den;
            }
        }
    }
}

extern "C" void kernel_launch(void* const* d_in, const int* in_sizes, int n_in,
                              void* d_out, int out_size, void* d_ws, size_t ws_size,
                              hipStream_t stream)
{
    const float* x  = (const float*)d_in[0];
    const float* Wq = (const float*)d_in[1];
    const float* bq = (const float*)d_in[2];
    const float* Wk = (const float*)d_in[3];
    const float* bk = (const float*)d_in[4];
    const float* Wv = (const float*)d_in[5];
    const float* bv = (const float*)d_in[6];
    const float* pb = (const float*)d_in[7];
    float* out = (float*)d_out;

    char* ws = (char*)d_ws;
    unsigned short* eb  = (unsigned short*)(ws);                          // 2 MiB
    unsigned short* Wb  = (unsigned short*)(ws + ((size_t)2   << 20));    // 1.5 MiB
    unsigned short* xb  = (unsigned short*)(ws + ((size_t)4   << 20));    // 64 MiB
    unsigned short* s   = (unsigned short*)(ws + ((size_t)68  << 20));    // 64 MiB
    unsigned short* Z   = (unsigned short*)(ws + ((size_t)132 << 20));    // 128 MiB

    k_eb <<<1024, 256, 0, stream>>>(pb, eb);
    k_cvt<<<16384, 256, 0, stream>>>(x,  xb);
    k_cvt<<<128,   256, 0, stream>>>(Wq, Wb);
    k_cvt_kv<<<128, 256, 0, stream>>>(Wk, Wb, 0);
    k_cvt_kv<<<128, 256, 0, stream>>>(Wv, Wb, 64);
    k_qkv<<<1536, 512, 131072, stream>>>(xb, Wb, bq, bk, bv, s, Z);
    k_aft<<<1024, 512, 131072, stream>>>(eb, Z, s, out);
}

// Round 7
// 341.077 us; speedup vs baseline: 1.0448x; 1.0448x over previous
//
#include <hip/hip_runtime.h>
#include <hip/hip_bf16.h>
#include <stdint.h>

// AFT-full, MI355X. Shapes: x[64,1024,512], W*[512,512], pos_bias[1024,1024].
//   q,k,v = x W^T + b ; out = sigmoid(q) * (eb@(e^k*v)) / (eb@e^k), eb=exp(pos_bias)
// Pipeline:
//   K0: eb = bf16(exp(pos_bias));  K1: xb = bf16(x), Wb = [Wq; Wk/Wv interleaved]
//   P1: fused QKV GEMM -> s (sigmoid(q), natural), Z (ekv/ek K-major interleaved)
//   P2: merged GEMM C[i,n] = eb @ Z^T, register-local num/den division epilogue.
// Both GEMMs: 256x256 tile, BK=32, 8 waves, 128 KiB LDS as 4 K-tile slots
// (depth-3 prefetch). Per tile: 2 phases {ds_read | 2 gl_lds | barrier |
// setprio + 16 MFMA | barrier}; ONE vmcnt(8) per tile (2 tiles stay in flight,
// never drained in-loop). Paired-row LDS layout: (r,c) at
// (r>>1)*64 + (r&1)*32 + ((c>>3) ^ ((r>>1)&3))*8 shorts -> frag reads are
// 2-way bank aliased (free); stage applies inverse permutation on global src.
// Workspace: eb 2MiB@0, Wb 1.5MiB@2MiB, xb 64MiB@4MiB, s 64MiB@68MiB, Z 128MiB@132MiB.

#define NSEQ 1024
#define DM   512

typedef __attribute__((ext_vector_type(8))) short bf16x8;
typedef __attribute__((ext_vector_type(4))) float f32x4;

static __device__ __forceinline__ float b2f(unsigned short u) {
    union { uint32_t i; float f; } c; c.i = ((uint32_t)u) << 16; return c.f;
}
static __device__ __forceinline__ unsigned short f2b(float f) {
    union { float f; uint32_t i; } c; c.f = f;
    uint32_t r = c.i + 0x7FFFu + ((c.i >> 16) & 1u);
    return (unsigned short)(r >> 16);
}
static __device__ __forceinline__ void gl_lds16(const unsigned short* g, unsigned short* l) {
    __builtin_amdgcn_global_load_lds(
        (const __attribute__((address_space(1))) unsigned int*)(g),
        (__attribute__((address_space(3))) unsigned int*)(l), 16, 0, 0);
}

__global__ void k_eb(const float* __restrict__ pb, unsigned short* __restrict__ eb) {
    int i = blockIdx.x * 256 + threadIdx.x;
    float4 v = reinterpret_cast<const float4*>(pb)[i];
    union { unsigned short u[4]; uint2 p; } o;
    o.u[0] = f2b(__expf(v.x)); o.u[1] = f2b(__expf(v.y));
    o.u[2] = f2b(__expf(v.z)); o.u[3] = f2b(__expf(v.w));
    reinterpret_cast<uint2*>(eb)[i] = o.p;
}

__global__ void k_cvt(const float* __restrict__ src, unsigned short* __restrict__ dst) {
    int i = blockIdx.x * 256 + threadIdx.x;
    const float4* p = reinterpret_cast<const float4*>(src) + (size_t)i * 2;
    float4 f0 = p[0], f1 = p[1];
    union { unsigned short u[8]; int4 v; } o;
    o.u[0]=f2b(f0.x); o.u[1]=f2b(f0.y); o.u[2]=f2b(f0.z); o.u[3]=f2b(f0.w);
    o.u[4]=f2b(f1.x); o.u[5]=f2b(f1.y); o.u[6]=f2b(f1.z); o.u[7]=f2b(f1.w);
    reinterpret_cast<int4*>(dst)[i] = o.v;
}

__global__ void k_cvt_kv(const float* __restrict__ src, unsigned short* __restrict__ Wb,
                         int toff) {
    int i = blockIdx.x * 256 + threadIdx.x;
    int r = i >> 6, c8 = i & 63;
    const float4* p = reinterpret_cast<const float4*>(src + (size_t)r * DM + c8 * 8);
    float4 f0 = p[0], f1 = p[1];
    union { unsigned short u[8]; int4 v; } o;
    o.u[0]=f2b(f0.x); o.u[1]=f2b(f0.y); o.u[2]=f2b(f0.z); o.u[3]=f2b(f0.w);
    o.u[4]=f2b(f1.x); o.u[5]=f2b(f1.y); o.u[6]=f2b(f1.z); o.u[7]=f2b(f1.w);
    int r2 = 512 + ((r >> 6) << 7) + toff + (r & 63);
    *reinterpret_cast<int4*>(&Wb[(size_t)r2 * DM + c8 * 8]) = o.v;
}

// ---------------- shared pipelined K-loop (BK=32, 4 slots, depth-3) ----------
// LDS shorts: A slot s @ s*8192 ; B slot s @ 32768 + s*8192. NT = K/32 (mult of 4).
// Ledger: prologue stages tiles 0,1,2 (12 loads/thread), vmcnt(8) forces tile0.
// Tile t: phA {read slot t&3 (B + A-h0) | stage A halves of t+3 | bar | MFMA | bar}
//         phB {read A-h1            | stage B halves of t+3 | vmcnt(8) | bar | MFMA | bar}
// Invariant at phB(t) wait: outstanding = tiles t+2,t+3 (8 loads) -> t+1 forced.
// WAR: tile t+3 overwrites slot of tile t-1, last read before phA(t) began.
// Tail stages in-bounds garbage (col wraps); final vmcnt(0)+bar before LDS reuse.
template<int NT>
static __device__ __forceinline__ void gemm_p(
    const unsigned short* __restrict__ Abase,
    const unsigned short* __restrict__ Bbase,
    int lda, int ldb, unsigned short* smem, f32x4 (&acc)[8][4],
    int wave, int lane)
{
    const int wr = wave >> 2, wq = wave & 3;
    const int lrow = lane & 15, lkg = lane >> 4;
    const int po  = lane >> 3;                 // row-pair offset within wave's 8
    const int sub = (lane >> 2) & 1;
    const int qp  = lane & 3;                  // LDS 16B-slot within 64-short pair-row

    auto stage = [&](int mat, int s, int h, int t) {
        int p = h * 64 + wave * 8 + po;        // row-pair 0..127
        int r = p * 2 + sub;                   // tile row 0..255
        int q = qp ^ (p & 3);                  // inverse of read-side swizzle
        int col = ((t & (NT - 1)) << 5) + q * 8;
        const unsigned short* g = (mat ? Bbase + (size_t)r * ldb
                                       : Abase + (size_t)r * lda) + col;
        unsigned short* d = smem + mat * 32768 + s * 8192 + (h * 64 + wave * 8) * 64;
        gl_lds16(g, d);                        // lane lands at +lane*16B
    };
    auto loadA = [&](int s, int h, bf16x8* af) {
        const unsigned short* base = smem + s * 8192;
        #pragma unroll
        for (int mi = 0; mi < 4; ++mi) {
            int r = wr * 128 + h * 64 + mi * 16 + lrow;
            int p = r >> 1;
            af[mi] = *reinterpret_cast<const bf16x8*>(
                base + p * 64 + (r & 1) * 32 + ((lkg ^ (p & 3)) << 3));
        }
    };
    auto loadB = [&](int s, bf16x8* bf) {
        const unsigned short* base = smem + 32768 + s * 8192;
        #pragma unroll
        for (int ni = 0; ni < 4; ++ni) {
            int r = wq * 64 + ni * 16 + lrow;
            int p = r >> 1;
            bf[ni] = *reinterpret_cast<const bf16x8*>(
                base + p * 64 + (r & 1) * 32 + ((lkg ^ (p & 3)) << 3));
        }
    };
    auto mfma16 = [&](int h, bf16x8* af, bf16x8* bf) {
        __builtin_amdgcn_s_setprio(1);
        #pragma unroll
        for (int mi = 0; mi < 4; ++mi)
            #pragma unroll
            for (int ni = 0; ni < 4; ++ni)
                acc[h * 4 + mi][ni] = __builtin_amdgcn_mfma_f32_16x16x32_bf16(
                    af[mi], bf[ni], acc[h * 4 + mi][ni], 0, 0, 0);
        __builtin_amdgcn_s_setprio(0);
    };

    // prologue: tiles 0,1,2 fully staged (12 loads/thread); force tile 0
    #pragma unroll
    for (int pt = 0; pt < 3; ++pt) {
        stage(0, pt, 0, pt); stage(0, pt, 1, pt);
        stage(1, pt, 0, pt); stage(1, pt, 1, pt);
    }
    asm volatile("s_waitcnt vmcnt(8)" ::: "memory");
    __builtin_amdgcn_s_barrier();

    #pragma unroll 1
    for (int tt = 0; tt < NT; tt += 4) {
        #pragma unroll
        for (int u = 0; u < 4; ++u) {
            const int t = tt + u;
            const int s = u, s3 = (u + 3) & 3, t3 = t + 3;
            bf16x8 af[4], bfr[4];
            // phA: B frags + A-h0 frags ; stage A halves of t+3
            loadB(s, bfr); loadA(s, 0, af);
            stage(0, s3, 0, t3); stage(0, s3, 1, t3);
            __builtin_amdgcn_s_barrier();
            mfma16(0, af, bfr);
            __builtin_amdgcn_s_barrier();
            // phB: A-h1 frags ; stage B halves of t+3 ; counted wait
            loadA(s, 1, af);
            stage(1, s3, 0, t3); stage(1, s3, 1, t3);
            asm volatile("s_waitcnt vmcnt(8)" ::: "memory");
            __builtin_amdgcn_s_barrier();
            mfma16(1, af, bfr);
            __builtin_amdgcn_s_barrier();
        }
    }
    asm volatile("s_waitcnt vmcnt(0)" ::: "memory");   // drain garbage tail
    __builtin_amdgcn_s_barrier();
}

// ---------------- P1: fused QKV projection ----------------
// 1536 blocks = 256 mtiles x 6 etiles; XCD-chunked, etile fastest.
__launch_bounds__(512)
__global__ void k_qkv(const unsigned short* __restrict__ xb,
                      const unsigned short* __restrict__ Wb,
                      const float* __restrict__ bq, const float* __restrict__ bk,
                      const float* __restrict__ bv,
                      unsigned short* __restrict__ s_out,
                      unsigned short* __restrict__ Z)
{
    extern __shared__ unsigned short smem[];          // 128 KiB
    const int bid = blockIdx.x;
    const int logical = (bid & 7) * 192 + (bid >> 3);
    const int mtile = logical / 6, etile = logical % 6;
    const int brow = mtile * 256;
    const int erow = etile * 256;
    const bool isq = (etile < 2);

    const int tid = threadIdx.x;
    const int lane = tid & 63, wave = tid >> 6;
    const int wr = wave >> 2, wq = wave & 3;
    const int lrow = lane & 15, lkg = lane >> 4;

    f32x4 acc[8][4];
    const f32x4 z4 = {0.f, 0.f, 0.f, 0.f};
    #pragma unroll
    for (int a = 0; a < 8; ++a)
        #pragma unroll
        for (int c = 0; c < 4; ++c) acc[a][c] = z4;

    gemm_p<16>(xb + (size_t)brow * DM, Wb + (size_t)erow * DM, DM, DM,
               smem, acc, wave, lane);

    unsigned short* T = smem;                          // [*][136] overlay
    if (isq) {
        const int ecol = etile * 256;
        #pragma unroll
        for (int pp = 0; pp < 2; ++pp) {
            __syncthreads();
            if ((wq >> 1) == pp) {
                #pragma unroll
                for (int mi = 0; mi < 8; ++mi) {
                    int m0 = wr*128 + mi*16 + lkg*4;
                    #pragma unroll
                    for (int ni = 0; ni < 4; ++ni) {
                        int nl = (wq & 1) * 64 + ni*16 + lrow;
                        float bia = bq[ecol + pp*128 + nl];
                        #pragma unroll
                        for (int r = 0; r < 4; ++r) {
                            float tq = acc[mi][ni][r] + bia;
                            float sg = __builtin_amdgcn_rcpf(1.f + __expf(-tq));
                            T[(m0 + r) * 136 + nl] = f2b(sg);
                        }
                    }
                }
            }
            __syncthreads();
            #pragma unroll
            for (int it = 0; it < 8; ++it) {
                int idx = it * 512 + tid;
                int m = idx >> 4, ng = idx & 15;
                int4 vv = *reinterpret_cast<const int4*>(&T[m * 136 + ng * 8]);
                *reinterpret_cast<int4*>(
                    &s_out[(size_t)(brow + m) * DM + ecol + pp*128 + ng * 8]) = vv;
            }
        }
    } else {
        const int gbase = (etile - 2) * 2;
        const int b = brow >> 10;
        #pragma unroll
        for (int pp = 0; pp < 2; ++pp) {              // m-half
            __syncthreads();
            if (wr == pp) {
                #pragma unroll
                for (int mi = 0; mi < 8; ++mi) {
                    int m0 = mi*16 + lkg*4;
                    #pragma unroll
                    for (int ni = 0; ni < 4; ++ni) {
                        int n = wq*64 + ni*16 + lrow;
                        int sub = (n >> 6) & 1, dr = n & 63;
                        int d = (gbase + (n >> 7)) * 64 + dr;
                        float bia = (sub == 0) ? bk[d] : bv[d];
                        union { unsigned short u[4]; uint2 p; } o;
                        #pragma unroll
                        for (int r = 0; r < 4; ++r) {
                            float tv = acc[mi][ni][r] + bia;
                            o.u[r] = f2b((sub == 0) ? __expf(tv) : tv);
                        }
                        *reinterpret_cast<uint2*>(&T[n * 136 + m0]) = o.p;
                    }
                }
            }
            __syncthreads();
            const int j0 = (brow & (NSEQ - 1)) + pp * 128;
            #pragma unroll
            for (int it = 0; it < 8; ++it) {
                int idx = it * 512 + tid;
                int zr = idx >> 4, jg = idx & 15;
                int gg = zr >> 7, sub2 = (zr >> 6) & 1, dr = zr & 63;
                int d = (gbase + gg) * 64 + dr;
                union { unsigned short u[8]; int4 v; } o;
                if (sub2 == 0) {
                    union { unsigned short u[8]; int4 v; } pe, pv;
                    pe.v = *reinterpret_cast<const int4*>(&T[(gg*128 + dr) * 136 + jg*8]);
                    pv.v = *reinterpret_cast<const int4*>(&T[(gg*128 + 64 + dr) * 136 + jg*8]);
                    #pragma unroll
                    for (int j = 0; j < 8; ++j) o.u[j] = f2b(b2f(pe.u[j]) * b2f(pv.u[j]));
                } else {
                    o.v = *reinterpret_cast<const int4*>(&T[(gg*128 + dr) * 136 + jg*8]);
                }
                int nn = ((d >> 4) << 5) + sub2 * 16 + (d & 15);
                size_t off = ((size_t)(b * NSEQ + nn)) * NSEQ + j0 + jg * 8;
                *reinterpret_cast<int4*>(&Z[off]) = o.v;
            }
        }
    }
}

// ---------------- P2: merged mixing GEMM ----------------
// 1024 blocks = 4 itiles x 256 ntiles, XCD-chunked, itile fastest.
__launch_bounds__(512)
__global__ void k_aft(const unsigned short* __restrict__ eb,
                      const unsigned short* __restrict__ Z,
                      const unsigned short* __restrict__ s_in,
                      float* __restrict__ out)
{
    extern __shared__ unsigned short smem[];          // 128 KiB
    const int bid = blockIdx.x;
    const int logical = (bid & 7) * 128 + (bid >> 3);
    const int itile = logical & 3, ntile = logical >> 2;
    const int i0 = itile * 256;
    const int n0 = ntile * 256;

    const int tid = threadIdx.x;
    const int lane = tid & 63, wave = tid >> 6;
    const int wr = wave >> 2, wq = wave & 3;
    const int lrow = lane & 15, lkg = lane >> 4;

    f32x4 acc[8][4];
    const f32x4 z4 = {0.f, 0.f, 0.f, 0.f};
    #pragma unroll
    for (int a = 0; a < 8; ++a)
        #pragma unroll
        for (int c = 0; c < 4; ++c) acc[a][c] = z4;

    gemm_p<32>(eb + (size_t)i0 * NSEQ, Z + (size_t)n0 * NSEQ, NSEQ, NSEQ,
               smem, acc, wave, lane);

    // epilogue: ni pairs (0,1),(2,3) are (num,den) for the same d
    #pragma unroll
    for (int mi = 0; mi < 8; ++mi) {
        int i = i0 + wr*128 + mi*16 + lkg*4;
        #pragma unroll
        for (int pi = 0; pi < 2; ++pi) {
            int nA = n0 + wq*64 + pi*32 + lrow;
            int b  = nA >> 10, nn = nA & (NSEQ - 1);
            int d  = ((nn >> 5) << 4) + (nn & 15);
            #pragma unroll
            for (int r = 0; r < 4; ++r) {
                size_t o = ((size_t)(b * NSEQ + i + r)) * DM + d;
                float num = acc[mi][pi*2][r];
                float den = acc[mi][pi*2 + 1][r];
                out[o] = b2f(s_in[o]) * num / den;
            }
        }
    }
}

extern "C" void kernel_launch(void* const* d_in, const int* in_sizes, int n_in,
                              void* d_out, int out_size, void* d_ws, size_t ws_size,
                              hipStream_t stream)
{
    const float* x  = (const float*)d_in[0];
    const float* Wq = (const float*)d_in[1];
    const float* bq = (const float*)d_in[2];
    const float* Wk = (const float*)d_in[3];
    const float* bk = (const float*)d_in[4];
    const float* Wv = (const float*)d_in[5];
    const float* bv = (const float*)d_in[6];
    const float* pb = (const float*)d_in[7];
    float* out = (float*)d_out;

    char* ws = (char*)d_ws;
    unsigned short* eb  = (unsigned short*)(ws);                          // 2 MiB
    unsigned short* Wb  = (unsigned short*)(ws + ((size_t)2   << 20));    // 1.5 MiB
    unsigned short* xb  = (unsigned short*)(ws + ((size_t)4   << 20));    // 64 MiB
    unsigned short* s   = (unsigned short*)(ws + ((size_t)68  << 20));    // 64 MiB
    unsigned short* Z   = (unsigned short*)(ws + ((size_t)132 << 20));    // 128 MiB

    k_eb <<<1024, 256, 0, stream>>>(pb, eb);
    k_cvt<<<16384, 256, 0, stream>>>(x,  xb);
    k_cvt<<<128,   256, 0, stream>>>(Wq, Wb);
    k_cvt_kv<<<128, 256, 0, stream>>>(Wk, Wb, 0);
    k_cvt_kv<<<128, 256, 0, stream>>>(Wv, Wb, 64);
    k_qkv<<<1536, 512, 131072, stream>>>(xb, Wb, bq, bk, bv, s, Z);
    k_aft<<<1024, 512, 131072, stream>>>(eb, Z, s, out);
}

// Round 8
// 334.099 us; speedup vs baseline: 1.0667x; 1.0209x over previous
//
#include <hip/hip_runtime.h>
#include <hip/hip_bf16.h>
#include <stdint.h>

// AFT-full, MI355X. Shapes: x[64,1024,512], W*[512,512], pos_bias[1024,1024].
//   q,k,v = x W^T + b ; out = sigmoid(q) * (eb@(e^k*v)) / (eb@e^k), eb=exp(pos_bias)
// Pipeline:
//   K0: eb = bf16(exp(pos_bias));  K1: xb = bf16(x), Wb = [Wq; Wk/Wv interleaved]
//   P1: fused QKV GEMM -> s (sigmoid(q), natural), Z (ekv/ek K-major interleaved)
//   P2: merged GEMM C[i,n] = eb @ Z^T, register-local num/den division epilogue.
// Both GEMMs: 256x256 tile, BK=32, 8 waves, 128 KiB LDS as 4 K-tile slots
// (depth-3 prefetch), paired-row swizzled LDS (bank-conflict-free, r7-verified).
// r8 schedule: ONE barrier per tile (32 MFMA/barrier). Per-wave vmcnt is the
// only per-wave guarantee; the single vmcnt(8)+s_barrier per tile is the
// cross-wave publication of slot t+1 AND the WAR fence for slot t-1 overwrite.
// Ledger: prologue stages t0,t1,t2 (12 loads), vmcnt(8) forces t0, barrier.
// Tile t: {read bfr/af0(t) | stage A(t+3) | MFMA h0 | read af1(t) |
//          stage B(t+3) | MFMA h1 | vmcnt(8) (forces t+1) | barrier}.
// Workspace: eb 2MiB@0, Wb 1.5MiB@2MiB, xb 64MiB@4MiB, s 64MiB@68MiB, Z 128MiB@132MiB.

#define NSEQ 1024
#define DM   512

typedef __attribute__((ext_vector_type(8))) short bf16x8;
typedef __attribute__((ext_vector_type(4))) float f32x4;

static __device__ __forceinline__ float b2f(unsigned short u) {
    union { uint32_t i; float f; } c; c.i = ((uint32_t)u) << 16; return c.f;
}
static __device__ __forceinline__ unsigned short f2b(float f) {
    union { float f; uint32_t i; } c; c.f = f;
    uint32_t r = c.i + 0x7FFFu + ((c.i >> 16) & 1u);
    return (unsigned short)(r >> 16);
}
static __device__ __forceinline__ void gl_lds16(const unsigned short* g, unsigned short* l) {
    __builtin_amdgcn_global_load_lds(
        (const __attribute__((address_space(1))) unsigned int*)(g),
        (__attribute__((address_space(3))) unsigned int*)(l), 16, 0, 0);
}

__global__ void k_eb(const float* __restrict__ pb, unsigned short* __restrict__ eb) {
    int i = blockIdx.x * 256 + threadIdx.x;
    float4 v = reinterpret_cast<const float4*>(pb)[i];
    union { unsigned short u[4]; uint2 p; } o;
    o.u[0] = f2b(__expf(v.x)); o.u[1] = f2b(__expf(v.y));
    o.u[2] = f2b(__expf(v.z)); o.u[3] = f2b(__expf(v.w));
    reinterpret_cast<uint2*>(eb)[i] = o.p;
}

__global__ void k_cvt(const float* __restrict__ src, unsigned short* __restrict__ dst) {
    int i = blockIdx.x * 256 + threadIdx.x;
    const float4* p = reinterpret_cast<const float4*>(src) + (size_t)i * 2;
    float4 f0 = p[0], f1 = p[1];
    union { unsigned short u[8]; int4 v; } o;
    o.u[0]=f2b(f0.x); o.u[1]=f2b(f0.y); o.u[2]=f2b(f0.z); o.u[3]=f2b(f0.w);
    o.u[4]=f2b(f1.x); o.u[5]=f2b(f1.y); o.u[6]=f2b(f1.z); o.u[7]=f2b(f1.w);
    reinterpret_cast<int4*>(dst)[i] = o.v;
}

__global__ void k_cvt_kv(const float* __restrict__ src, unsigned short* __restrict__ Wb,
                         int toff) {
    int i = blockIdx.x * 256 + threadIdx.x;
    int r = i >> 6, c8 = i & 63;
    const float4* p = reinterpret_cast<const float4*>(src + (size_t)r * DM + c8 * 8);
    float4 f0 = p[0], f1 = p[1];
    union { unsigned short u[8]; int4 v; } o;
    o.u[0]=f2b(f0.x); o.u[1]=f2b(f0.y); o.u[2]=f2b(f0.z); o.u[3]=f2b(f0.w);
    o.u[4]=f2b(f1.x); o.u[5]=f2b(f1.y); o.u[6]=f2b(f1.z); o.u[7]=f2b(f1.w);
    int r2 = 512 + ((r >> 6) << 7) + toff + (r & 63);
    *reinterpret_cast<int4*>(&Wb[(size_t)r2 * DM + c8 * 8]) = o.v;
}

// ---------------- shared pipelined K-loop (BK=32, 4 slots, depth-3) ----------
// LDS shorts: A slot s @ s*8192 ; B slot s @ 32768 + s*8192. NT = K/32 (mult of 4).
// Paired-row layout: (r,c) at (r>>1)*64 + (r&1)*32 + ((c>>3)^((r>>1)&3))*8 shorts;
// stage applies the inverse permutation on the global source (both-sides rule).
// ONE barrier per tile; vmcnt(8) forces tile t+1 resident before publication.
// WAR: stage(t+3) overwrites slot of t-1; all t-1 reads precede bar(t-1) < issue.
// Tail stages in-bounds garbage (col wraps); final vmcnt(0)+bar before LDS reuse.
template<int NT>
static __device__ __forceinline__ void gemm_p(
    const unsigned short* __restrict__ Abase,
    const unsigned short* __restrict__ Bbase,
    int lda, int ldb, unsigned short* smem, f32x4 (&acc)[8][4],
    int wave, int lane)
{
    const int wr = wave >> 2, wq = wave & 3;
    const int lrow = lane & 15, lkg = lane >> 4;
    const int po  = lane >> 3;                 // row-pair offset within wave's 8
    const int sub = (lane >> 2) & 1;
    const int qp  = lane & 3;                  // LDS 16B-slot within 64-short pair-row

    auto stage = [&](int mat, int s, int h, int t) {
        int p = h * 64 + wave * 8 + po;        // row-pair 0..127
        int r = p * 2 + sub;                   // tile row 0..255
        int q = qp ^ (p & 3);                  // inverse of read-side swizzle
        int col = ((t & (NT - 1)) << 5) + q * 8;
        const unsigned short* g = (mat ? Bbase + (size_t)r * ldb
                                       : Abase + (size_t)r * lda) + col;
        unsigned short* d = smem + mat * 32768 + s * 8192 + (h * 64 + wave * 8) * 64;
        gl_lds16(g, d);                        // lane lands at +lane*16B
    };
    auto loadA = [&](int s, int h, bf16x8* af) {
        const unsigned short* base = smem + s * 8192;
        #pragma unroll
        for (int mi = 0; mi < 4; ++mi) {
            int r = wr * 128 + h * 64 + mi * 16 + lrow;
            int p = r >> 1;
            af[mi] = *reinterpret_cast<const bf16x8*>(
                base + p * 64 + (r & 1) * 32 + ((lkg ^ (p & 3)) << 3));
        }
    };
    auto loadB = [&](int s, bf16x8* bf) {
        const unsigned short* base = smem + 32768 + s * 8192;
        #pragma unroll
        for (int ni = 0; ni < 4; ++ni) {
            int r = wq * 64 + ni * 16 + lrow;
            int p = r >> 1;
            bf[ni] = *reinterpret_cast<const bf16x8*>(
                base + p * 64 + (r & 1) * 32 + ((lkg ^ (p & 3)) << 3));
        }
    };
    auto mfma16 = [&](int h, bf16x8* af, bf16x8* bf) {
        __builtin_amdgcn_s_setprio(1);
        #pragma unroll
        for (int mi = 0; mi < 4; ++mi)
            #pragma unroll
            for (int ni = 0; ni < 4; ++ni)
                acc[h * 4 + mi][ni] = __builtin_amdgcn_mfma_f32_16x16x32_bf16(
                    af[mi], bf[ni], acc[h * 4 + mi][ni], 0, 0, 0);
        __builtin_amdgcn_s_setprio(0);
    };

    // prologue: tiles 0,1,2 fully staged (12 loads/thread); force tile 0; publish
    #pragma unroll
    for (int pt = 0; pt < 3; ++pt) {
        stage(0, pt, 0, pt); stage(0, pt, 1, pt);
        stage(1, pt, 0, pt); stage(1, pt, 1, pt);
    }
    asm volatile("s_waitcnt vmcnt(8)" ::: "memory");
    __builtin_amdgcn_s_barrier();

    #pragma unroll 1
    for (int tt = 0; tt < NT; tt += 4) {
        #pragma unroll
        for (int u = 0; u < 4; ++u) {
            const int t = tt + u;
            const int s = u, s3 = (u + 3) & 3, t3 = t + 3;
            bf16x8 af[4], bfr[4];
            // reads of slot s (published at bar of tile t-1) + A-prefetch of t+3
            loadB(s, bfr); loadA(s, 0, af);
            stage(0, s3, 0, t3); stage(0, s3, 1, t3);
            mfma16(0, af, bfr);
            // second M-half reads + B-prefetch of t+3
            loadA(s, 1, af);
            stage(1, s3, 0, t3); stage(1, s3, 1, t3);
            mfma16(1, af, bfr);
            // single per-tile publication: own t+1 loads done, then cross-wave
            asm volatile("s_waitcnt vmcnt(8)" ::: "memory");
            __builtin_amdgcn_s_barrier();
        }
    }
    asm volatile("s_waitcnt vmcnt(0)" ::: "memory");   // drain garbage tail
    __builtin_amdgcn_s_barrier();
}

// ---------------- P1: fused QKV projection ----------------
// 1536 blocks = 256 mtiles x 6 etiles; XCD-chunked, etile fastest.
__launch_bounds__(512)
__global__ void k_qkv(const unsigned short* __restrict__ xb,
                      const unsigned short* __restrict__ Wb,
                      const float* __restrict__ bq, const float* __restrict__ bk,
                      const float* __restrict__ bv,
                      unsigned short* __restrict__ s_out,
                      unsigned short* __restrict__ Z)
{
    extern __shared__ unsigned short smem[];          // 128 KiB
    const int bid = blockIdx.x;
    const int logical = (bid & 7) * 192 + (bid >> 3);
    const int mtile = logical / 6, etile = logical % 6;
    const int brow = mtile * 256;
    const int erow = etile * 256;
    const bool isq = (etile < 2);

    const int tid = threadIdx.x;
    const int lane = tid & 63, wave = tid >> 6;
    const int wr = wave >> 2, wq = wave & 3;
    const int lrow = lane & 15, lkg = lane >> 4;

    f32x4 acc[8][4];
    const f32x4 z4 = {0.f, 0.f, 0.f, 0.f};
    #pragma unroll
    for (int a = 0; a < 8; ++a)
        #pragma unroll
        for (int c = 0; c < 4; ++c) acc[a][c] = z4;

    gemm_p<16>(xb + (size_t)brow * DM, Wb + (size_t)erow * DM, DM, DM,
               smem, acc, wave, lane);

    unsigned short* T = smem;                          // [*][136] overlay
    if (isq) {
        const int ecol = etile * 256;
        #pragma unroll
        for (int pp = 0; pp < 2; ++pp) {
            __syncthreads();
            if ((wq >> 1) == pp) {
                #pragma unroll
                for (int mi = 0; mi < 8; ++mi) {
                    int m0 = wr*128 + mi*16 + lkg*4;
                    #pragma unroll
                    for (int ni = 0; ni < 4; ++ni) {
                        int nl = (wq & 1) * 64 + ni*16 + lrow;
                        float bia = bq[ecol + pp*128 + nl];
                        #pragma unroll
                        for (int r = 0; r < 4; ++r) {
                            float tq = acc[mi][ni][r] + bia;
                            float sg = __builtin_amdgcn_rcpf(1.f + __expf(-tq));
                            T[(m0 + r) * 136 + nl] = f2b(sg);
                        }
                    }
                }
            }
            __syncthreads();
            #pragma unroll
            for (int it = 0; it < 8; ++it) {
                int idx = it * 512 + tid;
                int m = idx >> 4, ng = idx & 15;
                int4 vv = *reinterpret_cast<const int4*>(&T[m * 136 + ng * 8]);
                *reinterpret_cast<int4*>(
                    &s_out[(size_t)(brow + m) * DM + ecol + pp*128 + ng * 8]) = vv;
            }
        }
    } else {
        const int gbase = (etile - 2) * 2;
        const int b = brow >> 10;
        #pragma unroll
        for (int pp = 0; pp < 2; ++pp) {              // m-half
            __syncthreads();
            if (wr == pp) {
                #pragma unroll
                for (int mi = 0; mi < 8; ++mi) {
                    int m0 = mi*16 + lkg*4;
                    #pragma unroll
                    for (int ni = 0; ni < 4; ++ni) {
                        int n = wq*64 + ni*16 + lrow;
                        int sub = (n >> 6) & 1, dr = n & 63;
                        int d = (gbase + (n >> 7)) * 64 + dr;
                        float bia = (sub == 0) ? bk[d] : bv[d];
                        union { unsigned short u[4]; uint2 p; } o;
                        #pragma unroll
                        for (int r = 0; r < 4; ++r) {
                            float tv = acc[mi][ni][r] + bia;
                            o.u[r] = f2b((sub == 0) ? __expf(tv) : tv);
                        }
                        *reinterpret_cast<uint2*>(&T[n * 136 + m0]) = o.p;
                    }
                }
            }
            __syncthreads();
            const int j0 = (brow & (NSEQ - 1)) + pp * 128;
            #pragma unroll
            for (int it = 0; it < 8; ++it) {
                int idx = it * 512 + tid;
                int zr = idx >> 4, jg = idx & 15;
                int gg = zr >> 7, sub2 = (zr >> 6) & 1, dr = zr & 63;
                int d = (gbase + gg) * 64 + dr;
                union { unsigned short u[8]; int4 v; } o;
                if (sub2 == 0) {
                    union { unsigned short u[8]; int4 v; } pe, pv;
                    pe.v = *reinterpret_cast<const int4*>(&T[(gg*128 + dr) * 136 + jg*8]);
                    pv.v = *reinterpret_cast<const int4*>(&T[(gg*128 + 64 + dr) * 136 + jg*8]);
                    #pragma unroll
                    for (int j = 0; j < 8; ++j) o.u[j] = f2b(b2f(pe.u[j]) * b2f(pv.u[j]));
                } else {
                    o.v = *reinterpret_cast<const int4*>(&T[(gg*128 + dr) * 136 + jg*8]);
                }
                int nn = ((d >> 4) << 5) + sub2 * 16 + (d & 15);
                size_t off = ((size_t)(b * NSEQ + nn)) * NSEQ + j0 + jg * 8;
                *reinterpret_cast<int4*>(&Z[off]) = o.v;
            }
        }
    }
}

// ---------------- P2: merged mixing GEMM ----------------
// 1024 blocks = 4 itiles x 256 ntiles, XCD-chunked, itile fastest.
__launch_bounds__(512)
__global__ void k_aft(const unsigned short* __restrict__ eb,
                      const unsigned short* __restrict__ Z,
                      const unsigned short* __restrict__ s_in,
                      float* __restrict__ out)
{
    extern __shared__ unsigned short smem[];          // 128 KiB
    const int bid = blockIdx.x;
    const int logical = (bid & 7) * 128 + (bid >> 3);
    const int itile = logical & 3, ntile = logical >> 2;
    const int i0 = itile * 256;
    const int n0 = ntile * 256;

    const int tid = threadIdx.x;
    const int lane = tid & 63, wave = tid >> 6;
    const int wr = wave >> 2, wq = wave & 3;
    const int lrow = lane & 15, lkg = lane >> 4;

    f32x4 acc[8][4];
    const f32x4 z4 = {0.f, 0.f, 0.f, 0.f};
    #pragma unroll
    for (int a = 0; a < 8; ++a)
        #pragma unroll
        for (int c = 0; c < 4; ++c) acc[a][c] = z4;

    gemm_p<32>(eb + (size_t)i0 * NSEQ, Z + (size_t)n0 * NSEQ, NSEQ, NSEQ,
               smem, acc, wave, lane);

    // epilogue: ni pairs (0,1),(2,3) are (num,den) for the same d
    #pragma unroll
    for (int mi = 0; mi < 8; ++mi) {
        int i = i0 + wr*128 + mi*16 + lkg*4;
        #pragma unroll
        for (int pi = 0; pi < 2; ++pi) {
            int nA = n0 + wq*64 + pi*32 + lrow;
            int b  = nA >> 10, nn = nA & (NSEQ - 1);
            int d  = ((nn >> 5) << 4) + (nn & 15);
            #pragma unroll
            for (int r = 0; r < 4; ++r) {
                size_t o = ((size_t)(b * NSEQ + i + r)) * DM + d;
                float num = acc[mi][pi*2][r];
                float den = acc[mi][pi*2 + 1][r];
                out[o] = b2f(s_in[o]) * num / den;
            }
        }
    }
}

extern "C" void kernel_launch(void* const* d_in, const int* in_sizes, int n_in,
                              void* d_out, int out_size, void* d_ws, size_t ws_size,
                              hipStream_t stream)
{
    const float* x  = (const float*)d_in[0];
    const float* Wq = (const float*)d_in[1];
    const float* bq = (const float*)d_in[2];
    const float* Wk = (const float*)d_in[3];
    const float* bk = (const float*)d_in[4];
    const float* Wv = (const float*)d_in[5];
    const float* bv = (const float*)d_in[6];
    const float* pb = (const float*)d_in[7];
    float* out = (float*)d_out;

    char* ws = (char*)d_ws;
    unsigned short* eb  = (unsigned short*)(ws);                          // 2 MiB
    unsigned short* Wb  = (unsigned short*)(ws + ((size_t)2   << 20));    // 1.5 MiB
    unsigned short* xb  = (unsigned short*)(ws + ((size_t)4   << 20));    // 64 MiB
    unsigned short* s   = (unsigned short*)(ws + ((size_t)68  << 20));    // 64 MiB
    unsigned short* Z   = (unsigned short*)(ws + ((size_t)132 << 20));    // 128 MiB

    k_eb <<<1024, 256, 0, stream>>>(pb, eb);
    k_cvt<<<16384, 256, 0, stream>>>(x,  xb);
    k_cvt<<<128,   256, 0, stream>>>(Wq, Wb);
    k_cvt_kv<<<128, 256, 0, stream>>>(Wk, Wb, 0);
    k_cvt_kv<<<128, 256, 0, stream>>>(Wv, Wb, 64);
    k_qkv<<<1536, 512, 131072, stream>>>(xb, Wb, bq, bk, bv, s, Z);
    k_aft<<<1024, 512, 131072, stream>>>(eb, Z, s, out);
}